// Round 11
// baseline (1127.359 us; speedup 1.0000x reference)
//
#include <hip/hip_runtime.h>
#include <math.h>

#define NR 131072
#define KC 1024
#define DD 256

// d_out element offsets (float32 elements)
#define ZQ_OFF  0
#define RES_OFF 33554432
#define IDX_OFF 67108864
#define LOSS_OFF 67239936
#define PERP_OFF 67239937

// ws byte offsets
#define WS_CNT 0         // int[1024]
#define WS_C2N 4096      // float[1024]
#define WS_Z2  8192      // float[131072]
#define WS_BSS 532480    // double[512]

#define FM(x,y) __fmul_rn((x),(y))
#define FA(x,y) __fadd_rn((x),(y))

// async global->LDS, 16B/lane; LDS dest = wave-uniform base + lane*16
static __device__ __forceinline__ void glds16(const float* g, float* l) {
  __builtin_amdgcn_global_load_lds(
      (const __attribute__((address_space(1))) void*)g,
      (__attribute__((address_space(3))) void*)l, 16, 0, 0);
}

// ---- numpy f32 pairwise sum-of-squares, one 128-block (AVX512 tree) --------
static __device__ __forceinline__ float np_sumsq128(const float* __restrict__ q) {
  float lane[16];
#pragma unroll
  for (int l = 0; l < 16; l++) {
    float s0 = FM(q[l +   0], q[l +   0]);
    float s1 = FM(q[l +  16], q[l +  16]);
    float s2 = FM(q[l +  32], q[l +  32]);
    float s3 = FM(q[l +  48], q[l +  48]);
    float s4 = FM(q[l +  64], q[l +  64]);
    float s5 = FM(q[l +  80], q[l +  80]);
    float s6 = FM(q[l +  96], q[l +  96]);
    float s7 = FM(q[l + 112], q[l + 112]);
    lane[l] = FA(FA(FA(s0, s1), FA(s2, s3)), FA(FA(s4, s5), FA(s6, s7)));
  }
#pragma unroll
  for (int h = 8; h >= 1; h >>= 1)
#pragma unroll
    for (int l = 0; l < 8; l++)
      if (l < h) lane[l] = FA(lane[l], lane[l + h]);
  return lane[0];
}

static __device__ __forceinline__ float np_sumsq256(const float* __restrict__ p) {
  return FA(np_sumsq128(p), np_sumsq128(p + 128));
}

// ---------------- K1a: codebook c2 (numpy-replica f32) ----------------------
__global__ void vq11_c2(const float* __restrict__ cb, float* __restrict__ c2n) {
  const int code = blockIdx.x * 256 + threadIdx.x;
  if (code < KC) c2n[code] = np_sumsq256(cb + (size_t)code * DD);
}

// ---------------- K1b: per-row z2, 16 threads/row, exact AVX512 tree --------
__global__ void vq11_z2(const float* __restrict__ z, float* __restrict__ z2g) {
  const int row = blockIdx.x * 16 + (threadIdx.x >> 4);
  const int l   = threadIdx.x & 15;
  const float* q = z + (size_t)row * DD;
  float blk[2];
#pragma unroll
  for (int b = 0; b < 2; b++) {
    const float* qq = q + b * 128;
    const float s0 = FM(qq[l +   0], qq[l +   0]);
    const float s1 = FM(qq[l +  16], qq[l +  16]);
    const float s2 = FM(qq[l +  32], qq[l +  32]);
    const float s3 = FM(qq[l +  48], qq[l +  48]);
    const float s4 = FM(qq[l +  64], qq[l +  64]);
    const float s5 = FM(qq[l +  80], qq[l +  80]);
    const float s6 = FM(qq[l +  96], qq[l +  96]);
    const float s7 = FM(qq[l + 112], qq[l + 112]);
    float v = FA(FA(FA(s0, s1), FA(s2, s3)), FA(FA(s4, s5), FA(s6, s7)));
#pragma unroll
    for (int h = 8; h >= 1; h >>= 1) v = FA(v, __shfl_down(v, h, 16));
    blk[b] = v;
  }
  if (l == 0) z2g[row] = FA(blk[0], blk[1]);
}

// ---------------- K2: pipelined np-f32 argmin + gather + outputs ------------
// 512 threads (8 waves), 256 rows/WG (512 WGs); 64 phases = 8 cbk x 8 kq.
// Double-buffered zt[2][256x32] + sc[2][128x32]; per phase each wave issues
// 6 glds for phase p+1, waits vmcnt(6) (own p-loads done), raw barrier,
// computes, trailing barrier. No vmcnt(0) drain in the main loop (T3/T4).
// Per-thread tile 8 rows x 8 codes. Bit-exact: each acc gets its 256 FMAs
// in ascending k (phase-major kq 0..7, k4 0..7, .x->.w) == np/BLAS chain.
__global__ __launch_bounds__(512, 2) void vq11_main(
    const float* __restrict__ z, const float* __restrict__ cb,
    const float* __restrict__ c2n, const float* __restrict__ z2g,
    float* __restrict__ out, int* __restrict__ counts,
    double* __restrict__ bss) {
  __shared__ __align__(16) float zt[2][8192];   // 65,536 B (buf0 reused for merge)
  __shared__ __align__(16) float sc[2][4096];   // 32,768 B
  __shared__ int rowidx[256];
  __shared__ double wred[8];

  const int tid = threadIdx.x;
  const int wg  = blockIdx.x;
  const int tw  = tid >> 4;            // 0..31 -> rows {tw+32i, i=0..7}
  const int tc  = tid & 15;            // 0..15 -> codes {tc+16j, j=0..7}
  const int wv  = tid >> 6;            // wave 0..7
  const int ln  = tid & 63;
  const size_t zwg = (size_t)wg * 256 * DD;

  const int xA = tw & 3;               // zt read swizzle ((tw+32i)&3 == tw&3)
  const int xB = tc & 7;               // sc read swizzle ((tc+16j)&7 == tc&7)

  float z2v[8];
#pragma unroll
  for (int i = 0; i < 8; i++) z2v[i] = z2g[wg * 256 + tw + 32 * i];

  float m1[8]; int i1[8];
#pragma unroll
  for (int i = 0; i < 8; i++) { m1[i] = INFINITY; i1[i] = 0; }

  float acc[8][8];

  // stage phase P (cbk=P>>3, kq=P&7) into buffer BUF: 6 glds per wave
#define STAGE(P, BUF) do {                                                   \
    const int cbk_ = (P) >> 3, kq_ = (P) & 7;                                \
    _Pragma("unroll")                                                        \
    for (int u = 0; u < 4; u++) {                                            \
      const int r0  = wv * 32 + u * 8;                                       \
      const int row = r0 + (ln >> 3);                                        \
      const int s   = ln & 7;                                                \
      glds16(z + zwg + (size_t)row * DD + kq_ * 32 + ((s ^ (row & 3)) << 2), \
             &zt[BUF][r0 * 32]);                                             \
    }                                                                        \
    _Pragma("unroll")                                                        \
    for (int u = 0; u < 2; u++) {                                            \
      const int c0   = wv * 16 + u * 8;                                      \
      const int code = c0 + (ln >> 3);                                       \
      const int s    = ln & 7;                                               \
      glds16(cb + (size_t)(cbk_ * 128 + code) * DD + kq_ * 32 +              \
                 ((s ^ (code & 7)) << 2),                                    \
             &sc[BUF][c0 * 32]);                                             \
    }                                                                        \
  } while (0)

  STAGE(0, 0);
#pragma unroll 1
  for (int p = 0; p < 64; p++) {
    const int kq  = p & 7;
    const int buf = p & 1;
    if (p < 63) {
      const int pn = p + 1;
      STAGE(pn, pn & 1);
      asm volatile("s_waitcnt vmcnt(6)" ::: "memory");   // own p-loads done
    } else {
      asm volatile("s_waitcnt vmcnt(0)" ::: "memory");
    }
    __builtin_amdgcn_sched_barrier(0);
    __builtin_amdgcn_s_barrier();                        // all waves' p-loads done

    if (kq == 0) {
#pragma unroll
      for (int i = 0; i < 8; i++)
#pragma unroll
        for (int j = 0; j < 8; j++) acc[i][j] = 0.f;
    }

    const float* ztb = zt[buf];
    const float* scb = sc[buf];
#pragma unroll 2
    for (int k4 = 0; k4 < 8; k4++) {
      const int sA = (k4 ^ xA) << 2;
      const int sB = (k4 ^ xB) << 2;
      float4 B[8];
#pragma unroll
      for (int j = 0; j < 8; j++)
        B[j] = *(const float4*)&scb[(tc + 16 * j) * 32 + sB];
#pragma unroll
      for (int i = 0; i < 8; i++) {
        const float4 Av = *(const float4*)&ztb[(tw + 32 * i) * 32 + sA];
        // strict ascending-k f32 FMA chain per (row, code)
#pragma unroll
        for (int j = 0; j < 8; j++) {
          acc[i][j] = __fmaf_rn(Av.x, B[j].x, acc[i][j]);
          acc[i][j] = __fmaf_rn(Av.y, B[j].y, acc[i][j]);
          acc[i][j] = __fmaf_rn(Av.z, B[j].z, acc[i][j]);
          acc[i][j] = __fmaf_rn(Av.w, B[j].w, acc[i][j]);
        }
      }
    }

    if (kq == 7) {
      // fold 128 codes: d = fl( fl(z2 - 2*dot) + c2 ), first-min ascending code
      const int cbk = p >> 3;
#pragma unroll
      for (int j = 0; j < 8; j++) {
        const int code = cbk * 128 + j * 16 + tc;
        const float c2v = c2n[code];
#pragma unroll
        for (int i = 0; i < 8; i++) {
          const float t1 = 2.0f * acc[i][j];           // exact (x2)
          const float d  = FA(FA(z2v[i], -t1), c2v);
          if (d < m1[i]) { m1[i] = d; i1[i] = code; }
        }
      }
    }
    __builtin_amdgcn_s_barrier();      // all reads of buf[p&1] done (reuse guard)
  }
#undef STAGE

  // ---- cross-thread first-min merge (lexicographic on (d, code)) ----
  float* redm1 = &zt[0][0];            // [256][16] floats (16 KB)
  int*   redi1 = (int*)&zt[0][4096];   // [256][16] ints   (16 KB)
#pragma unroll
  for (int i = 0; i < 8; i++) {
    const int r = tw + 32 * i;
    redm1[r * 16 + tc] = m1[i];
    redi1[r * 16 + tc] = i1[i];
  }
  __syncthreads();
  if (tid < 256) {
    float M1 = INFINITY; int I1 = 0x7FFFFFFF;
    for (int q = 0; q < 16; q++) {
      const float a = redm1[tid * 16 + q];
      const int  ia = redi1[tid * 16 + q];
      if (a < M1 || (a == M1 && ia < I1)) { M1 = a; I1 = ia; }
    }
    rowidx[tid] = I1;
    atomicAdd(&counts[I1], 1);
    out[IDX_OFF + wg * 256 + tid] = (float)I1;
  }
  __syncthreads();

  // ---- gather + zq_st / residual (float32) + loss partial ----
  float ss = 0.f;
#pragma unroll 1
  for (int g = 0; g < 2; g++) {
    const int rr  = g * 128 + (tid >> 2);   // row 0..255
    const int seg = tid & 3;                // 64-float segment
    const int id  = rowidx[rr];
    const size_t zrow = zwg + (size_t)rr * DD + seg * 64;
    const float4* zp = (const float4*)(z + zrow);
    const float4* qp = (const float4*)(cb + (size_t)id * DD + seg * 64);
#pragma unroll
    for (int u = 0; u < 16; u++) {
      const float4 r4 = zp[u];
      const float4 q4 = qp[u];
      float4 stv, rsv; float dq;
      stv.x = r4.x + (q4.x - r4.x); rsv.x = r4.x - q4.x; dq = q4.x - r4.x; ss = fmaf(dq, dq, ss);
      stv.y = r4.y + (q4.y - r4.y); rsv.y = r4.y - q4.y; dq = q4.y - r4.y; ss = fmaf(dq, dq, ss);
      stv.z = r4.z + (q4.z - r4.z); rsv.z = r4.z - q4.z; dq = q4.z - r4.z; ss = fmaf(dq, dq, ss);
      stv.w = r4.w + (q4.w - r4.w); rsv.w = r4.w - q4.w; dq = q4.w - r4.w; ss = fmaf(dq, dq, ss);
      *(float4*)(out + ZQ_OFF  + zrow + u * 4) = stv;
      *(float4*)(out + RES_OFF + zrow + u * 4) = rsv;
    }
  }
  double dss = (double)ss;
  for (int o = 32; o; o >>= 1) dss += __shfl_down(dss, o, 64);
  if (ln == 0) wred[wv] = dss;
  __syncthreads();
  if (tid == 0) {
    double t = 0.0;
#pragma unroll
    for (int w = 0; w < 8; w++) t += wred[w];
    bss[wg] = t;
  }
}

// ---------------- K3: scalars (loss, perplexity) ----------------------------
__global__ void vq11_final(const int* __restrict__ counts,
                           const double* __restrict__ bss,
                           float* __restrict__ out) {
  __shared__ double red[256];
  const int t = threadIdx.x;
  double s = 0.0;
  for (int i = t; i < 512; i += 256) s += bss[i];
  red[t] = s; __syncthreads();
  for (int s2 = 128; s2 > 0; s2 >>= 1) { if (t < s2) red[t] += red[t + s2]; __syncthreads(); }
  const double ssq = red[0];
  __syncthreads();
  double h = 0.0;
  for (int c = t; c < 1024; c += 256) {
    double p = (double)counts[c] / 131072.0;
    h += p * log(p + 1e-10);
  }
  red[t] = h; __syncthreads();
  for (int s2 = 128; s2 > 0; s2 >>= 1) { if (t < s2) red[t] += red[t + s2]; __syncthreads(); }
  if (t == 0) {
    out[LOSS_OFF] = (float)(0.25 * ssq / 33554432.0);
    out[PERP_OFF] = (float)exp(-red[0]);
  }
}

extern "C" void kernel_launch(void* const* d_in, const int* in_sizes, int n_in,
                              void* d_out, int out_size, void* d_ws, size_t ws_size,
                              hipStream_t stream) {
  // Bind inputs by SIZE: z has 33,554,432 elems, codebook 262,144.
  const float* z;
  const float* cb;
  if (in_sizes[0] == NR * DD) { z = (const float*)d_in[0]; cb = (const float*)d_in[1]; }
  else                        { cb = (const float*)d_in[0]; z = (const float*)d_in[1]; }

  float* out = (float*)d_out;
  char* ws = (char*)d_ws;
  int*    counts = (int*)(ws + WS_CNT);
  float*  c2n    = (float*)(ws + WS_C2N);
  float*  z2g    = (float*)(ws + WS_Z2);
  double* bss    = (double*)(ws + WS_BSS);

  hipMemsetAsync(counts, 0, 4096, stream);
  vq11_c2<<<4, 256, 0, stream>>>(cb, c2n);
  vq11_z2<<<NR / 16, 256, 0, stream>>>(z, z2g);
  vq11_main<<<NR / 256, 512, 0, stream>>>(z, cb, c2n, z2g, out, counts, bss);
  vq11_final<<<1, 256, 0, stream>>>(counts, bss, out);
}

// Round 12
// 501.747 us; speedup vs baseline: 2.2469x; 2.2469x over previous
//
#include <hip/hip_runtime.h>
#include <math.h>

#define NR 131072
#define KC 1024
#define DD 256

// d_out element offsets (float32 elements)
#define ZQ_OFF  0
#define RES_OFF 33554432
#define IDX_OFF 67108864
#define LOSS_OFF 67239936
#define PERP_OFF 67239937

// ws byte offsets (total ~1.55 MB)
#define WS_CNT 0          // int[1024]
#define WS_C2N 4096       // float[1024]
#define WS_Z2  8192       // float[131072]
#define WS_BSS 532480     // double[2048]
#define WS_CBS 548864     // ushort cb_split: 64 tiles x 16KB = 1 MB

#define MARG 3e-4f

#define FM(x,y) __fmul_rn((x),(y))
#define FA(x,y) __fadd_rn((x),(y))

typedef __attribute__((ext_vector_type(8))) short bf16x8;
typedef __attribute__((ext_vector_type(4))) float f32x4;

static __device__ __forceinline__ unsigned short bf16h(float f) {
  unsigned int u = __float_as_uint(f);
  u += 0x7FFFu + ((u >> 16) & 1u);
  return (unsigned short)(u >> 16);
}

// async global->LDS, 16B/lane; LDS dest = wave-uniform base + lane*16
static __device__ __forceinline__ void glds16(const void* g, void* l) {
  __builtin_amdgcn_global_load_lds(
      (const __attribute__((address_space(1))) void*)g,
      (__attribute__((address_space(3))) void*)l, 16, 0, 0);
}

// ---- numpy f32 pairwise sum-of-squares, one 128-block (AVX512 tree) --------
static __device__ __forceinline__ float np_sumsq128(const float* __restrict__ q) {
  float lane[16];
#pragma unroll
  for (int l = 0; l < 16; l++) {
    float s0 = FM(q[l +   0], q[l +   0]);
    float s1 = FM(q[l +  16], q[l +  16]);
    float s2 = FM(q[l +  32], q[l +  32]);
    float s3 = FM(q[l +  48], q[l +  48]);
    float s4 = FM(q[l +  64], q[l +  64]);
    float s5 = FM(q[l +  80], q[l +  80]);
    float s6 = FM(q[l +  96], q[l +  96]);
    float s7 = FM(q[l + 112], q[l + 112]);
    lane[l] = FA(FA(FA(s0, s1), FA(s2, s3)), FA(FA(s4, s5), FA(s6, s7)));
  }
#pragma unroll
  for (int h = 8; h >= 1; h >>= 1)
#pragma unroll
    for (int l = 0; l < 8; l++)
      if (l < h) lane[l] = FA(lane[l], lane[l + h]);
  return lane[0];
}

static __device__ __forceinline__ float np_sumsq256(const float* __restrict__ p) {
  return FA(np_sumsq128(p), np_sumsq128(p + 128));
}

// ---------------- K1a: codebook c2 (numpy-replica f32) ----------------------
__global__ void vqm_c2(const float* __restrict__ cb, float* __restrict__ c2n) {
  const int code = blockIdx.x * 256 + threadIdx.x;
  if (code < KC) c2n[code] = np_sumsq256(cb + (size_t)code * DD);
}

// ---------------- K1b: per-row z2, 16 threads/row, exact AVX512 tree --------
__global__ void vqm_z2(const float* __restrict__ z, float* __restrict__ z2g) {
  const int row = blockIdx.x * 16 + (threadIdx.x >> 4);
  const int l   = threadIdx.x & 15;
  const float* q = z + (size_t)row * DD;
  float blk[2];
#pragma unroll
  for (int b = 0; b < 2; b++) {
    const float* qq = q + b * 128;
    const float s0 = FM(qq[l +   0], qq[l +   0]);
    const float s1 = FM(qq[l +  16], qq[l +  16]);
    const float s2 = FM(qq[l +  32], qq[l +  32]);
    const float s3 = FM(qq[l +  48], qq[l +  48]);
    const float s4 = FM(qq[l +  64], qq[l +  64]);
    const float s5 = FM(qq[l +  80], qq[l +  80]);
    const float s6 = FM(qq[l +  96], qq[l +  96]);
    const float s7 = FM(qq[l + 112], qq[l + 112]);
    float v = FA(FA(FA(s0, s1), FA(s2, s3)), FA(FA(s4, s5), FA(s6, s7)));
#pragma unroll
    for (int h = 8; h >= 1; h >>= 1) v = FA(v, __shfl_down(v, h, 16));
    blk[b] = v;
  }
  if (l == 0) z2g[row] = FA(blk[0], blk[1]);
}

// ---------------- K1c: codebook bf16 hi/lo split, MFMA-granule layout -------
// Tile t (16 codes) = 16KB = 1024 granules of 16B. Granule g within tile:
// kc=g>>7, half=(g>>6)&1, q=(g>>4)&3, c=g&15 holds
// bf16_{half}(cb[t*16+c][kc*32+q*8+j]) j=0..7.  A-frag ds_read is then
// lane-linear: addr = (kc*2+half)*1024B + lane*16B  (zero bank conflicts).
__global__ void vqm_cbsplit(const float* __restrict__ cb,
                            unsigned short* __restrict__ cbs) {
  const int g  = blockIdx.x * 256 + threadIdx.x;   // 0..65535
  const int t  = g >> 10;
  const int gi = g & 1023;
  const int kc = gi >> 7, half = (gi >> 6) & 1, q = (gi >> 4) & 3, c = gi & 15;
  const float* src = cb + (size_t)(t * 16 + c) * DD + kc * 32 + q * 8;
  unsigned int w[4];
#pragma unroll
  for (int p = 0; p < 4; p++) {
    unsigned short v0, v1;
    float x0 = src[p * 2], x1 = src[p * 2 + 1];
    unsigned short h0 = bf16h(x0), h1 = bf16h(x1);
    if (half == 0) { v0 = h0; v1 = h1; }
    else {
      v0 = bf16h(x0 - __uint_as_float((unsigned int)h0 << 16));
      v1 = bf16h(x1 - __uint_as_float((unsigned int)h1 << 16));
    }
    w[p] = (unsigned int)v0 | ((unsigned int)v1 << 16);
  }
  *(uint4*)(cbs + (size_t)g * 8) = make_uint4(w[0], w[1], w[2], w[3]);
}

// ---------------- K2: MFMA screen + exact-np rescore + outputs --------------
// 64 rows/WG (2048 WGs), 4 waves; wave w owns rows w*16+(lane&15).
// 64 code-tiles of 16; per tile: 3 chained MFMAs x 8 K-chunks (hi*hi+hi*lo+
// lo*hi), fold d^ = z2 - 2*dot^ + c2, row-global running min, candidate
// append (margin MARG). Selection layer guarantees np-f32 bit-exactness:
// single filtered candidate -> argmin; else exact sequential-f32 np rescore.
__global__ __launch_bounds__(256, 3) void vqm_main(
    const float* __restrict__ z, const float* __restrict__ cb,
    const unsigned short* __restrict__ cbs,
    const float* __restrict__ c2n, const float* __restrict__ z2g,
    float* __restrict__ out, int* __restrict__ counts,
    double* __restrict__ bss) {
  __shared__ __align__(16) unsigned short ct[2][8192];  // 32 KB code-tile dbuf
  __shared__ unsigned short ccode[64][32];              //  4 KB
  __shared__ float cd[64][32];                          //  8 KB
  __shared__ int ccnt[64];
  __shared__ float m1row[64];
  __shared__ int rowidx[64];
  __shared__ double wred[4];

  const int tid = threadIdx.x, wg = blockIdx.x;
  const int wv = tid >> 6, ln = tid & 63;
  const int rl = ln & 15;           // row within wave's 16
  const int qk = ln >> 4;           // k-octet / code-quad selector
  const int rw = wv * 16 + rl;      // row local to WG
  const int rowg = wg * 64 + rw;    // global row
  const float z2v = z2g[rowg];

  // ---- build z fragments in registers: hi/lo bf16x8 per K-chunk ----
  bf16x8 zH[8], zL[8];
  {
    const float* zr = z + (size_t)rowg * DD;
#pragma unroll
    for (int kc = 0; kc < 8; kc++) {
      const float* p = zr + kc * 32 + qk * 8;
#pragma unroll
      for (int j = 0; j < 8; j++) {
        const float x = p[j];
        const unsigned short h = bf16h(x);
        zH[kc][j] = (short)h;
        zL[kc][j] = (short)bf16h(x - __uint_as_float((unsigned int)h << 16));
      }
    }
  }
  if (tid < 64) ccnt[tid] = 0;

#define STG(T, B) do {                                                        \
    _Pragma("unroll")                                                         \
    for (int r_ = 0; r_ < 4; r_++) {                                          \
      glds16(cbs + (size_t)(T) * 8192 + (size_t)(r_ * 256 + wv * 64 + ln) * 8,\
             &ct[B][(r_ * 256 + wv * 64) * 8]);                               \
    }                                                                         \
  } while (0)

  float m1 = INFINITY;
  STG(0, 0);
#pragma unroll 1
  for (int t = 0; t < 64; t++) {
    if (t < 63) {
      STG(t + 1, (t + 1) & 1);
      asm volatile("s_waitcnt vmcnt(4)" ::: "memory");  // tile-t loads done
    } else {
      asm volatile("s_waitcnt vmcnt(0)" ::: "memory");
    }
    __builtin_amdgcn_sched_barrier(0);
    __builtin_amdgcn_s_barrier();

    const unsigned short* cbuf = ct[t & 1];
    f32x4 a1 = {0.f, 0.f, 0.f, 0.f}, a2 = a1, a3 = a1;
#pragma unroll
    for (int kc = 0; kc < 8; kc++) {
      const bf16x8 aH = *(const bf16x8*)&cbuf[(kc * 2 + 0) * 512 + ln * 8];
      const bf16x8 aL = *(const bf16x8*)&cbuf[(kc * 2 + 1) * 512 + ln * 8];
      a1 = __builtin_amdgcn_mfma_f32_16x16x32_bf16(aH, zH[kc], a1, 0, 0, 0);
      a2 = __builtin_amdgcn_mfma_f32_16x16x32_bf16(aH, zL[kc], a2, 0, 0, 0);
      a3 = __builtin_amdgcn_mfma_f32_16x16x32_bf16(aL, zH[kc], a3, 0, 0, 0);
    }
    // fold: lane covers codes t*16 + qk*4 + r for row rl
    float dh[4];
#pragma unroll
    for (int r = 0; r < 4; r++) {
      const float dot = (a1[r] + a2[r]) + a3[r];
      dh[r] = z2v - 2.f * dot + c2n[t * 16 + qk * 4 + r];
      m1 = fminf(m1, dh[r]);
    }
    m1 = fminf(m1, __shfl_xor(m1, 16));
    m1 = fminf(m1, __shfl_xor(m1, 32));
#pragma unroll
    for (int r = 0; r < 4; r++) {
      if (dh[r] <= m1 + MARG) {
        const int s = atomicAdd(&ccnt[rw], 1);
        if (s < 32) {
          ccode[rw][s] = (unsigned short)(t * 16 + qk * 4 + r);
          cd[rw][s] = dh[r];
        }
      }
    }
    __builtin_amdgcn_s_barrier();     // buffer reuse guard
  }
#undef STG

  if (qk == 0) m1row[rw] = m1;
  __syncthreads();

  // ---- finalize: filter candidates; exact np rescore where needed ----
  if (tid < 64) {
    const int row = wg * 64 + tid;
    const float mf = m1row[tid] + MARG;
    const int nc = ccnt[tid];
    int best;
    if (nc > 32) {               // overflow (practically impossible): full scan
      const float* zr = z + (size_t)row * DD;
      const float z2r = z2g[row];
      float db = INFINITY; best = 0;
      for (int c = 0; c < KC; c++) {
        const float* cr = cb + (size_t)c * DD;
        float dot = 0.f;
#pragma unroll 8
        for (int k = 0; k < DD; k++) dot = __fmaf_rn(zr[k], cr[k], dot);
        const float t1 = 2.0f * dot;
        const float d = FA(FA(z2r, -t1), c2n[c]);
        if (d < db) { db = d; best = c; }          // ascending c: first-min
      }
    } else {
      int kept = 0, kcode = 0;
      for (int s = 0; s < nc; s++)
        if (cd[tid][s] <= mf) { kept++; kcode = ccode[tid][s]; }
      if (kept == 1) best = kcode;
      else {
        const float* zr = z + (size_t)row * DD;
        const float z2r = z2g[row];
        float db = INFINITY; int bi = 0x7FFFFFFF;
        for (int s = 0; s < nc; s++) {
          if (cd[tid][s] > mf) continue;
          const int c = ccode[tid][s];
          const float* cr = cb + (size_t)c * DD;
          float dot = 0.f;
#pragma unroll 8
          for (int k = 0; k < DD; k++) dot = __fmaf_rn(zr[k], cr[k], dot);
          const float t1 = 2.0f * dot;
          const float d = FA(FA(z2r, -t1), c2n[c]);   // exact np-f32 d
          if (d < db || (d == db && c < bi)) { db = d; bi = c; }
        }
        best = bi;
      }
    }
    rowidx[tid] = best;
    atomicAdd(&counts[best], 1);
    out[IDX_OFF + row] = (float)best;
  }
  __syncthreads();

  // ---- gather + zq_st / residual (float32) + loss partial ----
  const int rr  = tid >> 2;            // 0..63 row
  const int seg = tid & 3;             // 0..3, 64-float segment
  const int id  = rowidx[rr];
  const size_t zrow = (size_t)(wg * 64 + rr) * DD + seg * 64;
  const float4* zp = (const float4*)(z + zrow);
  const float4* qp = (const float4*)(cb + (size_t)id * DD + seg * 64);
  float ss = 0.f;
#pragma unroll
  for (int u = 0; u < 16; u++) {
    const float4 r4 = zp[u];
    const float4 q4 = qp[u];
    float4 stv, rsv; float dq;
    stv.x = r4.x + (q4.x - r4.x); rsv.x = r4.x - q4.x; dq = q4.x - r4.x; ss = fmaf(dq, dq, ss);
    stv.y = r4.y + (q4.y - r4.y); rsv.y = r4.y - q4.y; dq = q4.y - r4.y; ss = fmaf(dq, dq, ss);
    stv.z = r4.z + (q4.z - r4.z); rsv.z = r4.z - q4.z; dq = q4.z - r4.z; ss = fmaf(dq, dq, ss);
    stv.w = r4.w + (q4.w - r4.w); rsv.w = r4.w - q4.w; dq = q4.w - r4.w; ss = fmaf(dq, dq, ss);
    *(float4*)(out + ZQ_OFF  + zrow + u * 4) = stv;
    *(float4*)(out + RES_OFF + zrow + u * 4) = rsv;
  }
  double dss = (double)ss;
  for (int o = 32; o; o >>= 1) dss += __shfl_down(dss, o, 64);
  if (ln == 0) wred[wv] = dss;
  __syncthreads();
  if (tid == 0) bss[wg] = wred[0] + wred[1] + wred[2] + wred[3];
}

// ---------------- K3: scalars (loss, perplexity) ----------------------------
__global__ void vqm_final(const int* __restrict__ counts,
                          const double* __restrict__ bss,
                          float* __restrict__ out) {
  __shared__ double red[256];
  const int t = threadIdx.x;
  double s = 0.0;
  for (int i = t; i < 2048; i += 256) s += bss[i];
  red[t] = s; __syncthreads();
  for (int s2 = 128; s2 > 0; s2 >>= 1) { if (t < s2) red[t] += red[t + s2]; __syncthreads(); }
  const double ssq = red[0];
  __syncthreads();
  double h = 0.0;
  for (int c = t; c < 1024; c += 256) {
    double p = (double)counts[c] / 131072.0;
    h += p * log(p + 1e-10);
  }
  red[t] = h; __syncthreads();
  for (int s2 = 128; s2 > 0; s2 >>= 1) { if (t < s2) red[t] += red[t + s2]; __syncthreads(); }
  if (t == 0) {
    out[LOSS_OFF] = (float)(0.25 * ssq / 33554432.0);
    out[PERP_OFF] = (float)exp(-red[0]);
  }
}

extern "C" void kernel_launch(void* const* d_in, const int* in_sizes, int n_in,
                              void* d_out, int out_size, void* d_ws, size_t ws_size,
                              hipStream_t stream) {
  // Bind inputs by SIZE: z has 33,554,432 elems, codebook 262,144.
  const float* z;
  const float* cb;
  if (in_sizes[0] == NR * DD) { z = (const float*)d_in[0]; cb = (const float*)d_in[1]; }
  else                        { cb = (const float*)d_in[0]; z = (const float*)d_in[1]; }

  float* out = (float*)d_out;
  char* ws = (char*)d_ws;
  int*            counts = (int*)(ws + WS_CNT);
  float*          c2n    = (float*)(ws + WS_C2N);
  float*          z2g    = (float*)(ws + WS_Z2);
  double*         bssp   = (double*)(ws + WS_BSS);
  unsigned short* cbs    = (unsigned short*)(ws + WS_CBS);

  hipMemsetAsync(counts, 0, 4096, stream);
  vqm_c2<<<4, 256, 0, stream>>>(cb, c2n);
  vqm_cbsplit<<<256, 256, 0, stream>>>(cb, cbs);
  vqm_z2<<<NR / 16, 256, 0, stream>>>(z, z2g);
  vqm_main<<<NR / 64, 256, 0, stream>>>(z, cb, cbs, c2n, z2g, out, counts, bssp);
  vqm_final<<<1, 256, 0, stream>>>(counts, bssp, out);
}

// Round 13
// 370.435 us; speedup vs baseline: 3.0433x; 1.3545x over previous
//
#include <hip/hip_runtime.h>
#include <math.h>

#define NR 131072
#define KC 1024
#define DD 256

// d_out element offsets (float32 elements)
#define ZQ_OFF  0
#define RES_OFF 33554432
#define IDX_OFF 67108864
#define LOSS_OFF 67239936
#define PERP_OFF 67239937

// ws byte offsets (total ~1.04 MB)
#define WS_CNT 0          // int[1024]
#define WS_C2N 4096       // float[1024]
#define WS_Z2  8192       // float[131072]
#define WS_BSS 532480     // double[1024]
#define WS_CBS 540672     // ushort cbs hi-only: 64 tiles x 8KB = 512KB

#define MARG 5e-4f
#define CCAP 28

#define FM(x,y) __fmul_rn((x),(y))
#define FA(x,y) __fadd_rn((x),(y))

typedef __attribute__((ext_vector_type(8))) short bf16x8;
typedef __attribute__((ext_vector_type(4))) float f32x4;

static __device__ __forceinline__ unsigned short bf16h(float f) {
  unsigned int u = __float_as_uint(f);
  u += 0x7FFFu + ((u >> 16) & 1u);
  return (unsigned short)(u >> 16);
}

// async global->LDS, 16B/lane; LDS dest = wave-uniform base + lane*16
static __device__ __forceinline__ void glds16(const void* g, void* l) {
  __builtin_amdgcn_global_load_lds(
      (const __attribute__((address_space(1))) void*)g,
      (__attribute__((address_space(3))) void*)l, 16, 0, 0);
}

// ---- numpy f32 pairwise sum-of-squares, one 128-block (AVX512 tree) --------
static __device__ __forceinline__ float np_sumsq128(const float* __restrict__ q) {
  float lane[16];
#pragma unroll
  for (int l = 0; l < 16; l++) {
    float s0 = FM(q[l +   0], q[l +   0]);
    float s1 = FM(q[l +  16], q[l +  16]);
    float s2 = FM(q[l +  32], q[l +  32]);
    float s3 = FM(q[l +  48], q[l +  48]);
    float s4 = FM(q[l +  64], q[l +  64]);
    float s5 = FM(q[l +  80], q[l +  80]);
    float s6 = FM(q[l +  96], q[l +  96]);
    float s7 = FM(q[l + 112], q[l + 112]);
    lane[l] = FA(FA(FA(s0, s1), FA(s2, s3)), FA(FA(s4, s5), FA(s6, s7)));
  }
#pragma unroll
  for (int h = 8; h >= 1; h >>= 1)
#pragma unroll
    for (int l = 0; l < 8; l++)
      if (l < h) lane[l] = FA(lane[l], lane[l + h]);
  return lane[0];
}

static __device__ __forceinline__ float np_sumsq256(const float* __restrict__ p) {
  return FA(np_sumsq128(p), np_sumsq128(p + 128));
}

// ---------------- K1a: codebook c2 (numpy-replica f32) ----------------------
__global__ void vqn_c2(const float* __restrict__ cb, float* __restrict__ c2n) {
  const int code = blockIdx.x * 256 + threadIdx.x;
  if (code < KC) c2n[code] = np_sumsq256(cb + (size_t)code * DD);
}

// ---------------- K1b: per-row z2, 16 threads/row, exact AVX512 tree --------
__global__ void vqn_z2(const float* __restrict__ z, float* __restrict__ z2g) {
  const int row = blockIdx.x * 16 + (threadIdx.x >> 4);
  const int l   = threadIdx.x & 15;
  const float* q = z + (size_t)row * DD;
  float blk[2];
#pragma unroll
  for (int b = 0; b < 2; b++) {
    const float* qq = q + b * 128;
    const float s0 = FM(qq[l +   0], qq[l +   0]);
    const float s1 = FM(qq[l +  16], qq[l +  16]);
    const float s2 = FM(qq[l +  32], qq[l +  32]);
    const float s3 = FM(qq[l +  48], qq[l +  48]);
    const float s4 = FM(qq[l +  64], qq[l +  64]);
    const float s5 = FM(qq[l +  80], qq[l +  80]);
    const float s6 = FM(qq[l +  96], qq[l +  96]);
    const float s7 = FM(qq[l + 112], qq[l + 112]);
    float v = FA(FA(FA(s0, s1), FA(s2, s3)), FA(FA(s4, s5), FA(s6, s7)));
#pragma unroll
    for (int h = 8; h >= 1; h >>= 1) v = FA(v, __shfl_down(v, h, 16));
    blk[b] = v;
  }
  if (l == 0) z2g[row] = FA(blk[0], blk[1]);
}

// ---------------- K1c: codebook bf16 hi split, MFMA-granule layout ----------
// Tile t (16 codes) = 8KB = 512 granules of 16B. Granule gi within tile:
// kc=gi>>6, q=(gi>>4)&3, c=gi&15 holds bf16_hi(cb[t*16+c][kc*32+q*8+j]) j=0..7.
// A-frag ds_read is lane-linear: addr = kc*1024B + lane*16B (conflict-free).
__global__ void vqn_cbsplit(const float* __restrict__ cb,
                            unsigned short* __restrict__ cbs) {
  const int g  = blockIdx.x * 256 + threadIdx.x;   // 0..32767
  const int t  = g >> 9;
  const int gi = g & 511;
  const int kc = gi >> 6, q = (gi >> 4) & 3, c = gi & 15;
  const float* src = cb + (size_t)(t * 16 + c) * DD + kc * 32 + q * 8;
  unsigned int w[4];
#pragma unroll
  for (int p = 0; p < 4; p++)
    w[p] = (unsigned int)bf16h(src[p * 2]) |
           ((unsigned int)bf16h(src[p * 2 + 1]) << 16);
  *(uint4*)(cbs + (size_t)g * 8) = make_uint4(w[0], w[1], w[2], w[3]);
}

// ---------------- K2: 1-pass MFMA screen + exact-np rescore + outputs -------
// 128 rows/WG (1024 WGs), 4 waves; wave w owns row-groups {2w, 2w+1} (16 rows
// each; row = wv*32 + g*16 + (lane&15)). 64 code-tiles of 16; per tile per kc:
// one A-read (hi codes) feeds 2 MFMAs (one per row-group, z-hi in VGPRs).
// Selection layer guarantees np-f32 bit-exactness: candidates within MARG of
// the running min; single filtered candidate -> argmin; else exact
// sequential-f32 np rescore (lex (d, code) first-min).
__global__ __launch_bounds__(256, 4) void vqn_main(
    const float* __restrict__ z, const float* __restrict__ cb,
    const unsigned short* __restrict__ cbs,
    const float* __restrict__ c2n, const float* __restrict__ z2g,
    float* __restrict__ out, int* __restrict__ counts,
    double* __restrict__ bss) {
  __shared__ __align__(16) unsigned short ct[2][4096];  // 16 KB code-tile dbuf
  __shared__ unsigned short ccode[128][CCAP];           //  7 KB
  __shared__ float cd[128][CCAP];                       // 14 KB
  __shared__ int ccnt[128];
  __shared__ float m1row[128];
  __shared__ int rowidx[128];
  __shared__ double wred[4];

  const int tid = threadIdx.x, wg = blockIdx.x;
  const int wv = tid >> 6, ln = tid & 63;
  const int rl = ln & 15;           // row within group
  const int qk = ln >> 4;           // k-octet / code-quad selector
  const int rowg0 = wg * 128 + wv * 32 + rl;      // group 0 global row
  const float z2v0 = z2g[rowg0];
  const float z2v1 = z2g[rowg0 + 16];

  // ---- build z hi-fragments in registers for both row-groups ----
  bf16x8 zH0[8], zH1[8];
#pragma unroll
  for (int kc = 0; kc < 8; kc++) {
    const float4* p0 = (const float4*)(z + (size_t)rowg0 * DD + kc * 32 + qk * 8);
    const float4* p1 = (const float4*)(z + (size_t)(rowg0 + 16) * DD + kc * 32 + qk * 8);
    const float4 a0 = p0[0], b0 = p0[1];
    const float4 a1 = p1[0], b1 = p1[1];
    zH0[kc][0] = (short)bf16h(a0.x); zH0[kc][1] = (short)bf16h(a0.y);
    zH0[kc][2] = (short)bf16h(a0.z); zH0[kc][3] = (short)bf16h(a0.w);
    zH0[kc][4] = (short)bf16h(b0.x); zH0[kc][5] = (short)bf16h(b0.y);
    zH0[kc][6] = (short)bf16h(b0.z); zH0[kc][7] = (short)bf16h(b0.w);
    zH1[kc][0] = (short)bf16h(a1.x); zH1[kc][1] = (short)bf16h(a1.y);
    zH1[kc][2] = (short)bf16h(a1.z); zH1[kc][3] = (short)bf16h(a1.w);
    zH1[kc][4] = (short)bf16h(b1.x); zH1[kc][5] = (short)bf16h(b1.y);
    zH1[kc][6] = (short)bf16h(b1.z); zH1[kc][7] = (short)bf16h(b1.w);
  }
  if (tid < 128) ccnt[tid] = 0;

  // stage tile T into buffer B: 2 glds per wave (1KB each)
#define STG(T, B) do {                                                        \
    _Pragma("unroll")                                                         \
    for (int u_ = 0; u_ < 2; u_++) {                                          \
      glds16(cbs + (size_t)(T) * 4096 + (size_t)((wv * 2 + u_) * 64 + ln) * 8,\
             &ct[B][(wv * 2 + u_) * 512]);                                    \
    }                                                                         \
  } while (0)

  float m10 = INFINITY, m11 = INFINITY;
  STG(0, 0);
#pragma unroll 1
  for (int t = 0; t < 64; t++) {
    if (t < 63) {
      STG(t + 1, (t + 1) & 1);
      asm volatile("s_waitcnt vmcnt(2)" ::: "memory");  // tile-t loads done
    } else {
      asm volatile("s_waitcnt vmcnt(0)" ::: "memory");
    }
    __builtin_amdgcn_sched_barrier(0);
    __builtin_amdgcn_s_barrier();

    const unsigned short* cbuf = ct[t & 1];
    f32x4 accA = {0.f, 0.f, 0.f, 0.f}, accB = accA;
#pragma unroll
    for (int kc = 0; kc < 8; kc++) {
      const bf16x8 aH = *(const bf16x8*)&cbuf[kc * 512 + ln * 8];
      accA = __builtin_amdgcn_mfma_f32_16x16x32_bf16(aH, zH0[kc], accA, 0, 0, 0);
      accB = __builtin_amdgcn_mfma_f32_16x16x32_bf16(aH, zH1[kc], accB, 0, 0, 0);
    }
    // fold: lane covers codes t*16 + qk*4 + r, rows (group0, group1)
    float dh0[4], dh1[4];
#pragma unroll
    for (int r = 0; r < 4; r++) {
      const float c2v = c2n[t * 16 + qk * 4 + r];
      dh0[r] = z2v0 - 2.f * accA[r] + c2v;
      dh1[r] = z2v1 - 2.f * accB[r] + c2v;
      m10 = fminf(m10, dh0[r]);
      m11 = fminf(m11, dh1[r]);
    }
    m10 = fminf(m10, __shfl_xor(m10, 16));
    m10 = fminf(m10, __shfl_xor(m10, 32));
    m11 = fminf(m11, __shfl_xor(m11, 16));
    m11 = fminf(m11, __shfl_xor(m11, 32));
    const int rw0 = wv * 32 + rl;
#pragma unroll
    for (int r = 0; r < 4; r++) {
      if (dh0[r] <= m10 + MARG) {
        const int s = atomicAdd(&ccnt[rw0], 1);
        if (s < CCAP) {
          ccode[rw0][s] = (unsigned short)(t * 16 + qk * 4 + r);
          cd[rw0][s] = dh0[r];
        }
      }
      if (dh1[r] <= m11 + MARG) {
        const int s = atomicAdd(&ccnt[rw0 + 16], 1);
        if (s < CCAP) {
          ccode[rw0 + 16][s] = (unsigned short)(t * 16 + qk * 4 + r);
          cd[rw0 + 16][s] = dh1[r];
        }
      }
    }
    __builtin_amdgcn_s_barrier();     // buffer reuse guard
  }
#undef STG

  if (qk == 0) { m1row[wv * 32 + rl] = m10; m1row[wv * 32 + rl + 16] = m11; }
  __syncthreads();

  // ---- finalize: filter candidates; exact np rescore where needed ----
  if (tid < 128) {
    const int row = wg * 128 + tid;
    const float mf = m1row[tid] + MARG;
    const int nc = ccnt[tid];
    int best;
    if (nc > CCAP) {             // overflow (P~0): full exact np scan
      const float* zr = z + (size_t)row * DD;
      const float z2r = z2g[row];
      float db = INFINITY; best = 0;
      for (int c = 0; c < KC; c++) {
        const float* cr = cb + (size_t)c * DD;
        float dot = 0.f;
#pragma unroll 8
        for (int k = 0; k < DD; k++) dot = __fmaf_rn(zr[k], cr[k], dot);
        const float t1 = 2.0f * dot;
        const float d = FA(FA(z2r, -t1), c2n[c]);
        if (d < db) { db = d; best = c; }          // ascending c: first-min
      }
    } else {
      int kept = 0, kcode = 0;
      for (int s = 0; s < nc; s++)
        if (cd[tid][s] <= mf) { kept++; kcode = ccode[tid][s]; }
      if (kept == 1) best = kcode;
      else {
        const float* zr = z + (size_t)row * DD;
        const float z2r = z2g[row];
        float db = INFINITY; int bi = 0x7FFFFFFF;
        for (int s = 0; s < nc; s++) {
          if (cd[tid][s] > mf) continue;
          const int c = ccode[tid][s];
          const float* cr = cb + (size_t)c * DD;
          float dot = 0.f;
#pragma unroll 8
          for (int k = 0; k < DD; k++) dot = __fmaf_rn(zr[k], cr[k], dot);
          const float t1 = 2.0f * dot;
          const float d = FA(FA(z2r, -t1), c2n[c]);   // exact np-f32 d
          if (d < db || (d == db && c < bi)) { db = d; bi = c; }
        }
        best = bi;
      }
    }
    rowidx[tid] = best;
    atomicAdd(&counts[best], 1);
    out[IDX_OFF + row] = (float)best;
  }
  __syncthreads();

  // ---- gather + zq_st / residual (float32) + loss partial ----
  float ss = 0.f;
#pragma unroll 1
  for (int g = 0; g < 2; g++) {
    const int rr  = g * 64 + (tid >> 2);   // 0..127 row
    const int seg = tid & 3;               // 64-float segment
    const int id  = rowidx[rr];
    const size_t zrow = (size_t)(wg * 128 + rr) * DD + seg * 64;
    const float4* zp = (const float4*)(z + zrow);
    const float4* qp = (const float4*)(cb + (size_t)id * DD + seg * 64);
#pragma unroll
    for (int u = 0; u < 16; u++) {
      const float4 r4 = zp[u];
      const float4 q4 = qp[u];
      float4 stv, rsv; float dq;
      stv.x = r4.x + (q4.x - r4.x); rsv.x = r4.x - q4.x; dq = q4.x - r4.x; ss = fmaf(dq, dq, ss);
      stv.y = r4.y + (q4.y - r4.y); rsv.y = r4.y - q4.y; dq = q4.y - r4.y; ss = fmaf(dq, dq, ss);
      stv.z = r4.z + (q4.z - r4.z); rsv.z = r4.z - q4.z; dq = q4.z - r4.z; ss = fmaf(dq, dq, ss);
      stv.w = r4.w + (q4.w - r4.w); rsv.w = r4.w - q4.w; dq = q4.w - r4.w; ss = fmaf(dq, dq, ss);
      *(float4*)(out + ZQ_OFF  + zrow + u * 4) = stv;
      *(float4*)(out + RES_OFF + zrow + u * 4) = rsv;
    }
  }
  double dss = (double)ss;
  for (int o = 32; o; o >>= 1) dss += __shfl_down(dss, o, 64);
  if (ln == 0) wred[wv] = dss;
  __syncthreads();
  if (tid == 0) bss[wg] = wred[0] + wred[1] + wred[2] + wred[3];
}

// ---------------- K3: scalars (loss, perplexity) ----------------------------
__global__ void vqn_final(const int* __restrict__ counts,
                          const double* __restrict__ bss,
                          float* __restrict__ out) {
  __shared__ double red[256];
  const int t = threadIdx.x;
  double s = 0.0;
  for (int i = t; i < 1024; i += 256) s += bss[i];
  red[t] = s; __syncthreads();
  for (int s2 = 128; s2 > 0; s2 >>= 1) { if (t < s2) red[t] += red[t + s2]; __syncthreads(); }
  const double ssq = red[0];
  __syncthreads();
  double h = 0.0;
  for (int c = t; c < 1024; c += 256) {
    double p = (double)counts[c] / 131072.0;
    h += p * log(p + 1e-10);
  }
  red[t] = h; __syncthreads();
  for (int s2 = 128; s2 > 0; s2 >>= 1) { if (t < s2) red[t] += red[t + s2]; __syncthreads(); }
  if (t == 0) {
    out[LOSS_OFF] = (float)(0.25 * ssq / 33554432.0);
    out[PERP_OFF] = (float)exp(-red[0]);
  }
}

extern "C" void kernel_launch(void* const* d_in, const int* in_sizes, int n_in,
                              void* d_out, int out_size, void* d_ws, size_t ws_size,
                              hipStream_t stream) {
  // Bind inputs by SIZE: z has 33,554,432 elems, codebook 262,144.
  const float* z;
  const float* cb;
  if (in_sizes[0] == NR * DD) { z = (const float*)d_in[0]; cb = (const float*)d_in[1]; }
  else                        { cb = (const float*)d_in[0]; z = (const float*)d_in[1]; }

  float* out = (float*)d_out;
  char* ws = (char*)d_ws;
  int*            counts = (int*)(ws + WS_CNT);
  float*          c2n    = (float*)(ws + WS_C2N);
  float*          z2g    = (float*)(ws + WS_Z2);
  double*         bssp   = (double*)(ws + WS_BSS);
  unsigned short* cbs    = (unsigned short*)(ws + WS_CBS);

  hipMemsetAsync(counts, 0, 4096, stream);
  vqn_c2<<<4, 256, 0, stream>>>(cb, c2n);
  vqn_cbsplit<<<128, 256, 0, stream>>>(cb, cbs);
  vqn_z2<<<NR / 16, 256, 0, stream>>>(z, z2g);
  vqn_main<<<NR / 128, 256, 0, stream>>>(z, cb, cbs, c2n, z2g, out, counts, bssp);
  vqn_final<<<1, 256, 0, stream>>>(counts, bssp, out);
}

// Round 14
// 316.023 us; speedup vs baseline: 3.5673x; 1.1722x over previous
//
#include <hip/hip_runtime.h>
#include <math.h>

#define NR 131072
#define KC 1024
#define DD 256

// d_out element offsets (float32 elements)
#define ZQ_OFF  0
#define RES_OFF 33554432
#define IDX_OFF 67108864
#define LOSS_OFF 67239936
#define PERP_OFF 67239937

// ws byte offsets (total ~532 KB)
#define WS_CNT 0          // int[1024]
#define WS_C2N 4096       // float[1024]
#define WS_BSS 8192       // double[1024]
#define WS_CBS 16384      // ushort cbs hi-only: 64 tiles x 8KB = 512KB

#define MARG 5e-4f
#define CCAP 28

#define FM(x,y) __fmul_rn((x),(y))
#define FA(x,y) __fadd_rn((x),(y))

typedef __attribute__((ext_vector_type(8))) short bf16x8;
typedef __attribute__((ext_vector_type(4))) float f32x4;

static __device__ __forceinline__ unsigned short bf16h(float f) {
  unsigned int u = __float_as_uint(f);
  u += 0x7FFFu + ((u >> 16) & 1u);
  return (unsigned short)(u >> 16);
}

// async global->LDS, 16B/lane; LDS dest = wave-uniform base + lane*16
static __device__ __forceinline__ void glds16(const void* g, void* l) {
  __builtin_amdgcn_global_load_lds(
      (const __attribute__((address_space(1))) void*)g,
      (__attribute__((address_space(3))) void*)l, 16, 0, 0);
}

// ---- numpy f32 pairwise sum-of-squares, one 128-block (AVX512 tree) --------
static __device__ __forceinline__ float np_sumsq128(const float* __restrict__ q) {
  float lane[16];
#pragma unroll
  for (int l = 0; l < 16; l++) {
    float s0 = FM(q[l +   0], q[l +   0]);
    float s1 = FM(q[l +  16], q[l +  16]);
    float s2 = FM(q[l +  32], q[l +  32]);
    float s3 = FM(q[l +  48], q[l +  48]);
    float s4 = FM(q[l +  64], q[l +  64]);
    float s5 = FM(q[l +  80], q[l +  80]);
    float s6 = FM(q[l +  96], q[l +  96]);
    float s7 = FM(q[l + 112], q[l + 112]);
    lane[l] = FA(FA(FA(s0, s1), FA(s2, s3)), FA(FA(s4, s5), FA(s6, s7)));
  }
#pragma unroll
  for (int h = 8; h >= 1; h >>= 1)
#pragma unroll
    for (int l = 0; l < 8; l++)
      if (l < h) lane[l] = FA(lane[l], lane[l + h]);
  return lane[0];
}

static __device__ __forceinline__ float np_sumsq256(const float* __restrict__ p) {
  return FA(np_sumsq128(p), np_sumsq128(p + 128));
}

// ---------------- K1a: codebook c2 (numpy-replica f32) ----------------------
__global__ void vqo_c2(const float* __restrict__ cb, float* __restrict__ c2n) {
  const int code = blockIdx.x * 256 + threadIdx.x;
  if (code < KC) c2n[code] = np_sumsq256(cb + (size_t)code * DD);
}

// ---------------- K1b: codebook bf16 hi split, MFMA-granule layout ----------
// Tile t (16 codes) = 8KB = 512 granules of 16B. Granule gi within tile:
// kc=gi>>6, q=(gi>>4)&3, c=gi&15 holds bf16_hi(cb[t*16+c][kc*32+q*8+j]) j=0..7.
// A-frag ds_read is lane-linear: addr = kc*1024B + lane*16B (conflict-free).
__global__ void vqo_cbsplit(const float* __restrict__ cb,
                            unsigned short* __restrict__ cbs) {
  const int g  = blockIdx.x * 256 + threadIdx.x;   // 0..32767
  const int t  = g >> 9;
  const int gi = g & 511;
  const int kc = gi >> 6, q = (gi >> 4) & 3, c = gi & 15;
  const float* src = cb + (size_t)(t * 16 + c) * DD + kc * 32 + q * 8;
  unsigned int w[4];
#pragma unroll
  for (int p = 0; p < 4; p++)
    w[p] = (unsigned int)bf16h(src[p * 2]) |
           ((unsigned int)bf16h(src[p * 2 + 1]) << 16);
  *(uint4*)(cbs + (size_t)g * 8) = make_uint4(w[0], w[1], w[2], w[3]);
}

// ---------------- K2: 1-pass MFMA screen + exact-np rescore + outputs -------
// 128 rows/WG (1024 WGs), 4 waves; wave w owns row-groups {2w, 2w+1} (16 rows
// each; row = wv*32 + g*16 + (lane&15)). 64 code-tiles of 16; per tile per kc:
// one A-read (hi codes) feeds 2 MFMAs (one per row-group, z-hi in VGPRs).
// z2 computed in-prologue (exact np AVX512 tree, 16-lane groups). Selection
// layer guarantees np-f32 bit-exactness: candidates within MARG of running
// min; single filtered candidate -> argmin; else exact sequential-f32 np
// rescore (lex (d, code) first-min). Epilogue: one wave per row, fully
// coalesced 1KB-per-instruction gather/store.
__global__ __launch_bounds__(256, 4) void vqo_main(
    const float* __restrict__ z, const float* __restrict__ cb,
    const unsigned short* __restrict__ cbs,
    const float* __restrict__ c2n,
    float* __restrict__ out, int* __restrict__ counts,
    double* __restrict__ bss) {
  __shared__ __align__(16) unsigned short ct[2][4096];  // 16 KB code-tile dbuf
  __shared__ unsigned short ccode[128][CCAP];           //  7 KB
  __shared__ float cd[128][CCAP];                       // 14 KB
  __shared__ int ccnt[128];
  __shared__ float m1row[128];
  __shared__ float z2s[128];
  __shared__ int rowidx[128];
  __shared__ double wred[4];

  const int tid = threadIdx.x, wg = blockIdx.x;
  const int wv = tid >> 6, ln = tid & 63;
  const int rl = ln & 15;           // row within group
  const int qk = ln >> 4;           // k-octet / code-quad selector
  const int rowg0 = wg * 128 + wv * 32 + rl;      // group 0 global row

  // stage tile T into buffer B: 2 glds per wave (1KB each)
#define STG(T, B) do {                                                        \
    _Pragma("unroll")                                                         \
    for (int u_ = 0; u_ < 2; u_++) {                                          \
      glds16(cbs + (size_t)(T) * 4096 + (size_t)((wv * 2 + u_) * 64 + ln) * 8,\
             &ct[B][(wv * 2 + u_) * 512]);                                    \
    }                                                                         \
  } while (0)

  STG(0, 0);

  // ---- build z hi-fragments in registers for both row-groups ----
  bf16x8 zH0[8], zH1[8];
#pragma unroll
  for (int kc = 0; kc < 8; kc++) {
    const float4* p0 = (const float4*)(z + (size_t)rowg0 * DD + kc * 32 + qk * 8);
    const float4* p1 = (const float4*)(z + (size_t)(rowg0 + 16) * DD + kc * 32 + qk * 8);
    const float4 a0 = p0[0], b0 = p0[1];
    const float4 a1 = p1[0], b1 = p1[1];
    zH0[kc][0] = (short)bf16h(a0.x); zH0[kc][1] = (short)bf16h(a0.y);
    zH0[kc][2] = (short)bf16h(a0.z); zH0[kc][3] = (short)bf16h(a0.w);
    zH0[kc][4] = (short)bf16h(b0.x); zH0[kc][5] = (short)bf16h(b0.y);
    zH0[kc][6] = (short)bf16h(b0.z); zH0[kc][7] = (short)bf16h(b0.w);
    zH1[kc][0] = (short)bf16h(a1.x); zH1[kc][1] = (short)bf16h(a1.y);
    zH1[kc][2] = (short)bf16h(a1.z); zH1[kc][3] = (short)bf16h(a1.w);
    zH1[kc][4] = (short)bf16h(b1.x); zH1[kc][5] = (short)bf16h(b1.y);
    zH1[kc][6] = (short)bf16h(b1.z); zH1[kc][7] = (short)bf16h(b1.w);
  }

  // ---- in-prologue z2: exact np AVX512 tree, 16-lane groups ----
  {
    const int gg = ln >> 4, l = ln & 15;
#pragma unroll 1
    for (int g4 = 0; g4 < 8; g4++) {
      const int rlcl = wv * 32 + g4 * 4 + gg;
      const float* q = z + (size_t)(wg * 128 + rlcl) * DD;
      float blk[2];
#pragma unroll
      for (int b = 0; b < 2; b++) {
        const float* qq = q + b * 128;
        const float s0 = FM(qq[l +   0], qq[l +   0]);
        const float s1 = FM(qq[l +  16], qq[l +  16]);
        const float s2 = FM(qq[l +  32], qq[l +  32]);
        const float s3 = FM(qq[l +  48], qq[l +  48]);
        const float s4 = FM(qq[l +  64], qq[l +  64]);
        const float s5 = FM(qq[l +  80], qq[l +  80]);
        const float s6 = FM(qq[l +  96], qq[l +  96]);
        const float s7 = FM(qq[l + 112], qq[l + 112]);
        float v = FA(FA(FA(s0, s1), FA(s2, s3)), FA(FA(s4, s5), FA(s6, s7)));
#pragma unroll
        for (int h = 8; h >= 1; h >>= 1) v = FA(v, __shfl_down(v, h, 16));
        blk[b] = v;
      }
      if (l == 0) z2s[rlcl] = FA(blk[0], blk[1]);
    }
  }
  if (tid < 128) ccnt[tid] = 0;
  __syncthreads();            // z2s visible (also orders ccnt init)

  const float z2v0 = z2s[wv * 32 + rl];
  const float z2v1 = z2s[wv * 32 + rl + 16];

  float m10 = INFINITY, m11 = INFINITY;
#pragma unroll 1
  for (int t = 0; t < 64; t++) {
    if (t < 63) {
      STG(t + 1, (t + 1) & 1);
      asm volatile("s_waitcnt vmcnt(2)" ::: "memory");  // tile-t loads done
    } else {
      asm volatile("s_waitcnt vmcnt(0)" ::: "memory");
    }
    __builtin_amdgcn_sched_barrier(0);
    __builtin_amdgcn_s_barrier();

    const unsigned short* cbuf = ct[t & 1];
    f32x4 accA = {0.f, 0.f, 0.f, 0.f}, accB = accA;
#pragma unroll
    for (int kc = 0; kc < 8; kc++) {
      const bf16x8 aH = *(const bf16x8*)&cbuf[kc * 512 + ln * 8];
      accA = __builtin_amdgcn_mfma_f32_16x16x32_bf16(aH, zH0[kc], accA, 0, 0, 0);
      accB = __builtin_amdgcn_mfma_f32_16x16x32_bf16(aH, zH1[kc], accB, 0, 0, 0);
    }
    // fold: lane covers codes t*16 + qk*4 + r, rows (group0, group1)
    float dh0[4], dh1[4];
#pragma unroll
    for (int r = 0; r < 4; r++) {
      const float c2v = c2n[t * 16 + qk * 4 + r];
      dh0[r] = z2v0 - 2.f * accA[r] + c2v;
      dh1[r] = z2v1 - 2.f * accB[r] + c2v;
      m10 = fminf(m10, dh0[r]);
      m11 = fminf(m11, dh1[r]);
    }
    m10 = fminf(m10, __shfl_xor(m10, 16));
    m10 = fminf(m10, __shfl_xor(m10, 32));
    m11 = fminf(m11, __shfl_xor(m11, 16));
    m11 = fminf(m11, __shfl_xor(m11, 32));
    const int rw0 = wv * 32 + rl;
#pragma unroll
    for (int r = 0; r < 4; r++) {
      if (dh0[r] <= m10 + MARG) {
        const int s = atomicAdd(&ccnt[rw0], 1);
        if (s < CCAP) {
          ccode[rw0][s] = (unsigned short)(t * 16 + qk * 4 + r);
          cd[rw0][s] = dh0[r];
        }
      }
      if (dh1[r] <= m11 + MARG) {
        const int s = atomicAdd(&ccnt[rw0 + 16], 1);
        if (s < CCAP) {
          ccode[rw0 + 16][s] = (unsigned short)(t * 16 + qk * 4 + r);
          cd[rw0 + 16][s] = dh1[r];
        }
      }
    }
    __builtin_amdgcn_s_barrier();     // buffer reuse guard
  }
#undef STG

  if (qk == 0) { m1row[wv * 32 + rl] = m10; m1row[wv * 32 + rl + 16] = m11; }
  __syncthreads();

  // ---- finalize: filter candidates; exact np rescore where needed ----
  if (tid < 128) {
    const int row = wg * 128 + tid;
    const float mf = m1row[tid] + MARG;
    const int nc = ccnt[tid];
    int best;
    if (nc > CCAP) {             // overflow (P~0): full exact np scan
      const float* zr = z + (size_t)row * DD;
      const float z2r = z2s[tid];
      float db = INFINITY; best = 0;
      for (int c = 0; c < KC; c++) {
        const float* cr = cb + (size_t)c * DD;
        float dot = 0.f;
#pragma unroll 8
        for (int k = 0; k < DD; k++) dot = __fmaf_rn(zr[k], cr[k], dot);
        const float t1 = 2.0f * dot;
        const float d = FA(FA(z2r, -t1), c2n[c]);
        if (d < db) { db = d; best = c; }          // ascending c: first-min
      }
    } else {
      int kept = 0, kcode = 0;
      for (int s = 0; s < nc; s++)
        if (cd[tid][s] <= mf) { kept++; kcode = ccode[tid][s]; }
      if (kept == 1) best = kcode;
      else {
        const float* zr = z + (size_t)row * DD;
        const float z2r = z2s[tid];
        float db = INFINITY; int bi = 0x7FFFFFFF;
        for (int s = 0; s < nc; s++) {
          if (cd[tid][s] > mf) continue;
          const int c = ccode[tid][s];
          const float* cr = cb + (size_t)c * DD;
          float dot = 0.f;
#pragma unroll 8
          for (int k = 0; k < DD; k++) dot = __fmaf_rn(zr[k], cr[k], dot);
          const float t1 = 2.0f * dot;
          const float d = FA(FA(z2r, -t1), c2n[c]);   // exact np-f32 d
          if (d < db || (d == db && c < bi)) { db = d; bi = c; }
        }
        best = bi;
      }
    }
    rowidx[tid] = best;
    atomicAdd(&counts[best], 1);
    out[IDX_OFF + row] = (float)best;
  }
  __syncthreads();

  // ---- gather + zq_st / residual: one wave per row, fully coalesced ----
  float ss = 0.f;
#pragma unroll 1
  for (int g = 0; g < 32; g++) {
    const int rlcl = wv * 32 + g;
    const int id   = rowidx[rlcl];
    const size_t zrow = (size_t)(wg * 128 + rlcl) * DD;
    const float4 r4 = ((const float4*)(z  + zrow))[ln];
    const float4 q4 = ((const float4*)(cb + (size_t)id * DD))[ln];
    float4 stv, rsv; float dq;
    stv.x = r4.x + (q4.x - r4.x); rsv.x = r4.x - q4.x; dq = q4.x - r4.x; ss = fmaf(dq, dq, ss);
    stv.y = r4.y + (q4.y - r4.y); rsv.y = r4.y - q4.y; dq = q4.y - r4.y; ss = fmaf(dq, dq, ss);
    stv.z = r4.z + (q4.z - r4.z); rsv.z = r4.z - q4.z; dq = q4.z - r4.z; ss = fmaf(dq, dq, ss);
    stv.w = r4.w + (q4.w - r4.w); rsv.w = r4.w - q4.w; dq = q4.w - r4.w; ss = fmaf(dq, dq, ss);
    ((float4*)(out + ZQ_OFF  + zrow))[ln] = stv;
    ((float4*)(out + RES_OFF + zrow))[ln] = rsv;
  }
  double dss = (double)ss;
  for (int o = 32; o; o >>= 1) dss += __shfl_down(dss, o, 64);
  if (ln == 0) wred[wv] = dss;
  __syncthreads();
  if (tid == 0) bss[wg] = wred[0] + wred[1] + wred[2] + wred[3];
}

// ---------------- K3: scalars (loss, perplexity) ----------------------------
__global__ void vqo_final(const int* __restrict__ counts,
                          const double* __restrict__ bss,
                          float* __restrict__ out) {
  __shared__ double red[256];
  const int t = threadIdx.x;
  double s = 0.0;
  for (int i = t; i < 1024; i += 256) s += bss[i];
  red[t] = s; __syncthreads();
  for (int s2 = 128; s2 > 0; s2 >>= 1) { if (t < s2) red[t] += red[t + s2]; __syncthreads(); }
  const double ssq = red[0];
  __syncthreads();
  double h = 0.0;
  for (int c = t; c < 1024; c += 256) {
    double p = (double)counts[c] / 131072.0;
    h += p * log(p + 1e-10);
  }
  red[t] = h; __syncthreads();
  for (int s2 = 128; s2 > 0; s2 >>= 1) { if (t < s2) red[t] += red[t + s2]; __syncthreads(); }
  if (t == 0) {
    out[LOSS_OFF] = (float)(0.25 * ssq / 33554432.0);
    out[PERP_OFF] = (float)exp(-red[0]);
  }
}

extern "C" void kernel_launch(void* const* d_in, const int* in_sizes, int n_in,
                              void* d_out, int out_size, void* d_ws, size_t ws_size,
                              hipStream_t stream) {
  // Bind inputs by SIZE: z has 33,554,432 elems, codebook 262,144.
  const float* z;
  const float* cb;
  if (in_sizes[0] == NR * DD) { z = (const float*)d_in[0]; cb = (const float*)d_in[1]; }
  else                        { cb = (const float*)d_in[0]; z = (const float*)d_in[1]; }

  float* out = (float*)d_out;
  char* ws = (char*)d_ws;
  int*            counts = (int*)(ws + WS_CNT);
  float*          c2n    = (float*)(ws + WS_C2N);
  double*         bssp   = (double*)(ws + WS_BSS);
  unsigned short* cbs    = (unsigned short*)(ws + WS_CBS);

  hipMemsetAsync(counts, 0, 4096, stream);
  vqo_c2<<<4, 256, 0, stream>>>(cb, c2n);
  vqo_cbsplit<<<128, 256, 0, stream>>>(cb, cbs);
  vqo_main<<<NR / 128, 256, 0, stream>>>(z, cb, cbs, c2n, out, counts, bssp);
  vqo_final<<<1, 256, 0, stream>>>(counts, bssp, out);
}